// Round 1
// baseline (672.520 us; speedup 1.0000x reference)
//
#include <hip/hip_runtime.h>

#define E_EDGES   500000
#define N_NODES   100000
#define MEM_DIM   100
#define TIME_DIM  100
#define HIDDEN    100

#define ROW_PAD   128        // padded bf16 row length for memory
#define KSTEPS    12         // 3 sections x 4 ksteps of K=32 (K padded 300->384)
#define NT        7          // 7 n-tiles of 16 = 112 padded cols (HIDDEN 100->112)

#define WG        512
#define WAVES     8
#define GRID      256
#define JOBS      (E_EDGES / 32)   // 15625, exact

#define WS_MEM16_OFF   86016                       // w1frag first: KSTEPS*NT*64*16 B
#define WS_NEEDED      (WS_MEM16_OFF + (size_t)N_NODES * ROW_PAD * 2)

typedef __attribute__((ext_vector_type(4))) float f32x4;
typedef __attribute__((ext_vector_type(8))) short bf16x8;

__device__ __forceinline__ unsigned short f2bf(float x) {
    union { float f; unsigned int u; } v; v.f = x;
    unsigned int r = v.u + 0x7fffu + ((v.u >> 16) & 1u);   // round-to-nearest-even
    return (unsigned short)(r >> 16);
}

// ---- setup 1: memory [N,100] f32 -> [N,128] bf16 (zero-padded) ----
__global__ void build_mem_bf16(const float* __restrict__ mem, uint4* __restrict__ outv) {
    int idx = blockIdx.x * blockDim.x + threadIdx.x;     // chunk = node*16 + c (8 elems each)
    if (idx >= N_NODES * (ROW_PAD / 8)) return;
    int node = idx >> 4;
    int k0   = (idx & 15) * 8;
    const float* row = mem + (size_t)node * MEM_DIM;
    unsigned short r[8];
#pragma unroll
    for (int j = 0; j < 8; ++j) {
        int k = k0 + j;
        float v = (k < MEM_DIM) ? row[k] : 0.0f;
        r[j] = f2bf(v);
    }
    uint4 o;
    o.x = (unsigned)r[0] | ((unsigned)r[1] << 16);
    o.y = (unsigned)r[2] | ((unsigned)r[3] << 16);
    o.z = (unsigned)r[4] | ((unsigned)r[5] << 16);
    o.w = (unsigned)r[6] | ((unsigned)r[7] << 16);
    outv[idx] = o;
}

// ---- setup 2: W1 [300,100] f32 -> B-fragment layout bf16 ----
// frag (ks,n), lane l, elem j  =  W1[sec*100 + kl][n*16 + (l&15)]  where
// kk = ks*32 + (l>>4)*8 + j, sec = kk>>7, kl = kk&127; zero outside valid range.
__global__ void build_w1frag(const float* __restrict__ W1, uint4* __restrict__ outv) {
    int idx = blockIdx.x * blockDim.x + threadIdx.x;     // (ks*NT + n)*64 + lane
    if (idx >= KSTEPS * NT * 64) return;
    int lane = idx & 63;
    int fid  = idx >> 6;
    int n    = fid % NT;
    int ks   = fid / NT;
    int col  = n * 16 + (lane & 15);
    int kb   = ks * 32 + (lane >> 4) * 8;
    unsigned short r[8];
#pragma unroll
    for (int j = 0; j < 8; ++j) {
        int kk  = kb + j;
        int sec = kk >> 7;
        int kl  = kk & 127;
        float v = 0.0f;
        if (kl < 100 && col < HIDDEN) v = W1[(size_t)(sec * 100 + kl) * HIDDEN + col];
        r[j] = f2bf(v);
    }
    uint4 o;
    o.x = (unsigned)r[0] | ((unsigned)r[1] << 16);
    o.y = (unsigned)r[2] | ((unsigned)r[3] << 16);
    o.z = (unsigned)r[4] | ((unsigned)r[5] << 16);
    o.w = (unsigned)r[6] | ((unsigned)r[7] << 16);
    outv[idx] = o;
}

// ---- main ----
__device__ __forceinline__ void mfma_step(const uint4* sm, int ks, int lane,
                                          bf16x8 a0, bf16x8 a1,
                                          f32x4* acc0, f32x4* acc1) {
    const bf16x8* bp = (const bf16x8*)(sm + (ks * NT) * 64 + lane);
#pragma unroll
    for (int n = 0; n < NT; ++n) {
        bf16x8 b = bp[n * 64];
        acc0[n] = __builtin_amdgcn_mfma_f32_16x16x32_bf16(a0, b, acc0[n], 0, 0, 0);
        acc1[n] = __builtin_amdgcn_mfma_f32_16x16x32_bf16(a1, b, acc1[n], 0, 0, 0);
    }
}

__launch_bounds__(WG, 2)
__global__ void tgn_main(const int* __restrict__ src, const int* __restrict__ dst,
                         const float* __restrict__ t, const float* __restrict__ last_update,
                         const float* __restrict__ time_w, const float* __restrict__ time_b,
                         const float* __restrict__ b1, const float* __restrict__ W2,
                         const float* __restrict__ b2,
                         const unsigned short* __restrict__ mem16,
                         const uint4* __restrict__ w1frag,
                         float* __restrict__ out) {
    extern __shared__ uint4 sm[];                        // [KSTEPS*NT*64] = 86016 B
    int tid = threadIdx.x;
    for (int i = tid; i < KSTEPS * NT * 64; i += WG) sm[i] = w1frag[i];
    __syncthreads();

    int lane = tid & 63;
    int wid  = tid >> 6;
    int c = lane & 15;                                   // A row within frag / B col within tile
    int g = lane >> 4;                                   // k-group

    // job-invariant epilogue params
    float b1v[NT], w20[NT], w21[NT], w22[NT];
#pragma unroll
    for (int n = 0; n < NT; ++n) {
        int col = n * 16 + c;
        bool val = col < HIDDEN;
        b1v[n] = val ? b1[col] : 0.0f;
        w20[n] = val ? W2[col * 3 + 0] : 0.0f;
        w21[n] = val ? W2[col * 3 + 1] : 0.0f;
        w22[n] = val ? W2[col * 3 + 2] : 0.0f;
    }
    float b20 = b2[0], b21 = b2[1], b22 = b2[2];

    int waveId     = blockIdx.x * WAVES + wid;
    int waveStride = gridDim.x * WAVES;

    for (int job = waveId; job < JOBS; job += waveStride) {
        int e0 = job * 32 + c;
        int e1 = e0 + 16;
        int s0 = src[e0], s1 = src[e1];
        int d0 = dst[e0], d1 = dst[e1];
        float dt0 = t[e0] - last_update[s0];
        float dt1 = t[e1] - last_update[s1];

        const bf16x8* pS0 = (const bf16x8*)(mem16 + (size_t)s0 * ROW_PAD) + g;
        const bf16x8* pS1 = (const bf16x8*)(mem16 + (size_t)s1 * ROW_PAD) + g;
        const bf16x8* pD0 = (const bf16x8*)(mem16 + (size_t)d0 * ROW_PAD) + g;
        const bf16x8* pD1 = (const bf16x8*)(mem16 + (size_t)d1 * ROW_PAD) + g;

        f32x4 acc0[NT], acc1[NT];
#pragma unroll
        for (int n = 0; n < NT; ++n) {
            acc0[n] = f32x4{0.0f, 0.0f, 0.0f, 0.0f};
            acc1[n] = f32x4{0.0f, 0.0f, 0.0f, 0.0f};
        }

        // section 0: src memory (ks 0..3) — direct global A-frag loads
#pragma unroll
        for (int q = 0; q < 4; ++q)
            mfma_step(sm, q, lane, pS0[q * 4], pS1[q * 4], acc0, acc1);

        // section 1: dst memory (ks 4..7)
#pragma unroll
        for (int q = 0; q < 4; ++q)
            mfma_step(sm, 4 + q, lane, pD0[q * 4], pD1[q * 4], acc0, acc1);

        // section 2: time encoding (ks 8..11) — computed in-register
#pragma unroll
        for (int q = 0; q < 4; ++q) {
            int kl = q * 32 + g * 8;
            bf16x8 a0, a1;
#pragma unroll
            for (int j = 0; j < 8; ++j) {
                int k = kl + j;
                bool val = k < TIME_DIM;
                float tw = val ? time_w[k] : 0.0f;
                float tb = val ? time_b[k] : 0.0f;
                float c0 = __cosf(fmaf(dt0, tw, tb));
                float c1 = __cosf(fmaf(dt1, tw, tb));
                a0[j] = val ? (short)f2bf(c0) : (short)0;
                a1[j] = val ? (short)f2bf(c1) : (short)0;
            }
            mfma_step(sm, 8 + q, lane, a0, a1, acc0, acc1);
        }

        // epilogue: h = relu(acc + b1); out = h @ W2 + b2
        float p[24];                                     // [half*12 + r*3 + o]
#pragma unroll
        for (int i = 0; i < 24; ++i) p[i] = 0.0f;
#pragma unroll
        for (int n = 0; n < NT; ++n) {
#pragma unroll
            for (int r = 0; r < 4; ++r) {
                float h0 = fmaxf(acc0[n][r] + b1v[n], 0.0f);
                float h1 = fmaxf(acc1[n][r] + b1v[n], 0.0f);
                p[r * 3 + 0]      += h0 * w20[n];
                p[r * 3 + 1]      += h0 * w21[n];
                p[r * 3 + 2]      += h0 * w22[n];
                p[12 + r * 3 + 0] += h1 * w20[n];
                p[12 + r * 3 + 1] += h1 * w21[n];
                p[12 + r * 3 + 2] += h1 * w22[n];
            }
        }
        // reduce over the 16 columns (lanes sharing g)
#pragma unroll
        for (int m = 1; m <= 8; m <<= 1)
#pragma unroll
            for (int i = 0; i < 24; ++i)
                p[i] += __shfl_xor(p[i], m, 64);

        if (c == 0) {
            // C/D layout: lane(row group g) reg r -> row g*4+r; halves 0/1 -> +0/+16
#pragma unroll
            for (int h = 0; h < 2; ++h) {
                const float* q = p + h * 12;
                float* op = out + ((size_t)job * 32 + h * 16 + g * 4) * 3;
                float4 v0 = make_float4(q[0] + b20, q[1] + b21, q[2] + b22, q[3] + b20);
                float4 v1 = make_float4(q[4] + b21, q[5] + b22, q[6] + b20, q[7] + b21);
                float4 v2 = make_float4(q[8] + b22, q[9] + b20, q[10] + b21, q[11] + b22);
                ((float4*)op)[0] = v0;
                ((float4*)op)[1] = v1;
                ((float4*)op)[2] = v2;
            }
        }
    }
}

extern "C" void kernel_launch(void* const* d_in, const int* in_sizes, int n_in,
                              void* d_out, int out_size, void* d_ws, size_t ws_size,
                              hipStream_t stream) {
    const int*   src         = (const int*)d_in[0];
    const int*   dst         = (const int*)d_in[1];
    const float* t           = (const float*)d_in[2];
    // d_in[3] = edge_attr: unused by the reference
    const float* memory      = (const float*)d_in[4];
    const float* last_update = (const float*)d_in[5];
    const float* time_w      = (const float*)d_in[6];
    const float* time_b      = (const float*)d_in[7];
    const float* W1          = (const float*)d_in[8];
    const float* b1          = (const float*)d_in[9];
    const float* W2          = (const float*)d_in[10];
    const float* b2          = (const float*)d_in[11];
    float*       out         = (float*)d_out;

    if (ws_size < WS_NEEDED) return;   // fail loud (validation will catch) rather than corrupt

    uint4*          w1frag = (uint4*)d_ws;
    unsigned short* mem16  = (unsigned short*)((char*)d_ws + WS_MEM16_OFF);

    build_mem_bf16<<<(N_NODES * (ROW_PAD / 8) + 255) / 256, 256, 0, stream>>>(memory, (uint4*)mem16);
    build_w1frag<<<(KSTEPS * NT * 64 + 255) / 256, 256, 0, stream>>>(W1, w1frag);

    (void)hipFuncSetAttribute((const void*)tgn_main,
                              hipFuncAttributeMaxDynamicSharedMemorySize,
                              KSTEPS * NT * 64 * 16);
    tgn_main<<<GRID, WG, KSTEPS * NT * 64 * 16, stream>>>(
        src, dst, t, last_update, time_w, time_b, b1, W2, b2, mem16, w1frag, out);
}